// Round 3
// baseline (107.231 us; speedup 1.0000x reference)
//
#include <hip/hip_runtime.h>

// Problem constants (N=1, C=64, H=W=80)
#define LDIM 6400
#define CDIM 64
#define WDIM 80
#define NEGV -1e9f
#define SCALE 0.15625f   // 1/(sqrt(64)*sqrt(64)*0.1) = 1/6.4

typedef unsigned short u16;
typedef unsigned long long u64;
typedef __attribute__((ext_vector_type(8))) short bf16x8;   // 8 bf16 = 4 VGPRs
typedef __attribute__((ext_vector_type(4))) float f32x4;
typedef __attribute__((ext_vector_type(4))) unsigned uint4e;

// Workspace layout (bytes). NO buffer requires pre-zeroing (no atomics).
#define COLE_OFF 0                                  // 6400 u32 (encoded colmax)
#define AHI_OFF  25600                              // 16B aligned
#define ARR_BYTES (LDIM * CDIM * 2)                 // 819200 per bf16 array
#define ALO_OFF  (AHI_OFF + ARR_BYTES)
#define BHI_OFF  (ALO_OFF + ARR_BYTES)
#define BLO_OFF  (BHI_OFF + ARR_BYTES)
#define ROWPART_OFF (BLO_OFF + ARR_BYTES)           // 50*6400 u64 partials
#define COLPART_OFF (ROWPART_OFF + 50 * LDIM * 8)   // 50*6400 f32 partials
#define WS_NEEDED   (COLPART_OFF + 50 * LDIM * 4)   // ~7.15 MB

// Orderable (ascending) encoding of fp32.
__device__ __forceinline__ unsigned encf(float f) {
    unsigned b = __float_as_uint(f);
    return (b & 0x80000000u) ? ~b : (b | 0x80000000u);
}
__device__ __forceinline__ float decf(unsigned e) {
    unsigned b = (e & 0x80000000u) ? (e ^ 0x80000000u) : ~e;
    return __uint_as_float(b);
}

// Split fp32 into bf16 hi (truncated, exact in f32) + bf16 lo (RNE of residual).
__device__ __forceinline__ void splitbf(float a, u16& h, u16& l) {
    unsigned ub = __float_as_uint(a);
    unsigned hb = ub & 0xFFFF0000u;
    float lof = a - __uint_as_float(hb);      // exact
    unsigned lb_ = __float_as_uint(lof);
    h = (u16)(hb >> 16);
    l = (u16)((lb_ + 0x7FFFu + ((lb_ >> 16) & 1u)) >> 16);
}

// prep: mkpts0 + convert A,B -> FRAG-MAJOR bf16 hi/lo.
// Frag-major layout (u16 units): elem(row l, k) at
//   (l>>4)*1024 + ks*512 + g*128 + (l&15)*8 + e   where k = ks*32 + g*8 + e.
// => a wave's 16x32 MFMA fragment is ONE contiguous 1KB load at base+lane*16.
__global__ __launch_bounds__(256) void prep_kernel(
        const float* __restrict__ A, const float* __restrict__ B,
        u16* __restrict__ Ahi, u16* __restrict__ Alo,
        u16* __restrict__ Bhi, u16* __restrict__ Blo,
        float* __restrict__ out) {
    int bi = blockIdx.x;
    const float* src;
    u16 *dhi, *dlo;
    bool isA = bi < 100;
    if (isA) { src = A; dhi = Ahi; dlo = Alo; }
    else     { src = B; dhi = Bhi; dlo = Blo; bi -= 100; }
    const int t = threadIdx.x;
    const int l = bi * 64 + (t & 63);
    const int kq = t >> 6;                      // 0..3: k in [kq*16, kq*16+16)
    const int ks = kq >> 1;                     // k-step (32-wide)
    const int g0 = (kq & 1) * 2;                // first of two 8-wide chunks

    unsigned hp[8], lp[8];
    #pragma unroll
    for (int m = 0; m < 8; ++m) {
        int k = kq * 16 + 2 * m;
        u16 h0, l0, h1, l1;
        splitbf(src[k * LDIM + l], h0, l0);
        splitbf(src[(k + 1) * LDIM + l], h1, l1);
        hp[m] = (unsigned)h0 | ((unsigned)h1 << 16);
        lp[m] = (unsigned)l0 | ((unsigned)l1 << 16);
    }
    size_t base = (size_t)(l >> 4) * 1024 + (size_t)ks * 512 + (size_t)(l & 15) * 8;
    *(uint4e*)(dhi + base + g0 * 128)       = (uint4e){hp[0], hp[1], hp[2], hp[3]};
    *(uint4e*)(dhi + base + (g0 + 1) * 128) = (uint4e){hp[4], hp[5], hp[6], hp[7]};
    *(uint4e*)(dlo + base + g0 * 128)       = (uint4e){lp[0], lp[1], lp[2], lp[3]};
    *(uint4e*)(dlo + base + (g0 + 1) * 128) = (uint4e){lp[4], lp[5], lp[6], lp[7]};

    if (isA && kq == 0) {
        out[2 * l]     = (float)((l % WDIM) * 8);
        out[2 * l + 1] = (float)((l / WDIM) * 8);
    }
}

// main (MFMA v3): blocks [0,2500) = 128x128 conf tiles, 512 threads = 8 waves
// in 2(lhalf) x 4(sq); wave tile 64(l) x 32(s). Operand-swapped MFMA:
// D = mfma(Bfrag, Afrag) -> D[row=s][col=l], per lane (g=lane>>4, l15=lane&15):
//   s = sb + sq*32 + j*16 + g*4 + r   (in-lane row-argmax)
//   l = lb + lhalf*64 + i*16 + l15    (cross-lane col-max via LDS)
// NO GLOBAL ATOMICS: per-block row/col partials go to workspace as plain
// coalesced stores (fire-and-forget); fcol/frow kernels reduce the 50 partials.
// Blocks [2500,3300) = bilinear x8 upsample (backfills the tail).
__global__ __launch_bounds__(512, 4) void main_mfma(
        const u16* __restrict__ Ahi, const u16* __restrict__ Alo,
        const u16* __restrict__ Bhi, const u16* __restrict__ Blo,
        const float* __restrict__ sav, const float* __restrict__ sai,
        u64* __restrict__ rowpart, float* __restrict__ colpart,
        float* __restrict__ out) {
    const int tid = threadIdx.x;
    const int b = blockIdx.x;

    if (b >= 2500) {
        // ---- upsample path ----
        int i = (b - 2500) * 512 + tid;   // < 640*640 = 409600, exact
        int oy = i / 640, ox = i % 640;
        const float step = 79.0f / 639.0f;
        float fy = (float)oy * step;
        float fx = (float)ox * step;
        int y0 = (int)floorf(fy); if (y0 > 79) y0 = 79; if (y0 < 0) y0 = 0;
        int x0 = (int)floorf(fx); if (x0 > 79) x0 = 79; if (x0 < 0) x0 = 0;
        int y1 = (y0 + 1 < 80) ? y0 + 1 : 79;
        int x1 = (x0 + 1 < 80) ? x0 + 1 : 79;
        float wy = fy - (float)y0;
        float wx = fx - (float)x0;
        float v00 = sai[y0 * 80 + x0], v01 = sai[y0 * 80 + x1];
        float v10 = sai[y1 * 80 + x0], v11 = sai[y1 * 80 + x1];
        float r0 = v00 * (1.0f - wy) + v10 * wy;
        float r1 = v01 * (1.0f - wy) + v11 * wy;
        out[38400 + i] = r0 * (1.0f - wx) + r1 * wx;
        return;
    }

    __shared__ u64   rowbuf[128][17];   // [l_local][sq*4+g], pad 17 -> 2-way scan
    __shared__ float colbuf[128][33];   // [s_local][lhalf*16+l15], pad 33 -> 2-way

    // ---- conf tile path ----
    const int lbi = b / 50, sbi = b % 50;
    const int lb = lbi * 128;
    const int sb = sbi * 128;
    const int lane = tid & 63, wid = tid >> 6;
    const int l15 = lane & 15, g = lane >> 4;
    const int lhalf = wid >> 2, sq = wid & 3;

    f32x4 acc[4][2];
    #pragma unroll
    for (int i = 0; i < 4; ++i)
        #pragma unroll
        for (int j = 0; j < 2; ++j)
            #pragma unroll
            for (int e = 0; e < 4; ++e) acc[i][j][e] = 0.0f;

    // frag-major bases (u16 units); one coalesced 1KB load per fragment
    const u16* pAh = Ahi + (size_t)(lb / 16 + lhalf * 4) * 1024 + lane * 8;
    const u16* pAl = Alo + (size_t)(lb / 16 + lhalf * 4) * 1024 + lane * 8;
    const u16* pBh = Bhi + (size_t)(sb / 16 + sq * 2) * 1024 + lane * 8;
    const u16* pBl = Blo + (size_t)(sb / 16 + sq * 2) * 1024 + lane * 8;

    #pragma unroll
    for (int ks = 0; ks < 2; ++ks) {
        bf16x8 ah[4], al[4], bh[2], bl[2];
        #pragma unroll
        for (int i = 0; i < 4; ++i) {
            ah[i] = *(const bf16x8*)(pAh + (size_t)i * 1024 + ks * 512);
            al[i] = *(const bf16x8*)(pAl + (size_t)i * 1024 + ks * 512);
        }
        #pragma unroll
        for (int j = 0; j < 2; ++j) {
            bh[j] = *(const bf16x8*)(pBh + (size_t)j * 1024 + ks * 512);
            bl[j] = *(const bf16x8*)(pBl + (size_t)j * 1024 + ks * 512);
        }
        #pragma unroll
        for (int i = 0; i < 4; ++i)
            #pragma unroll
            for (int j = 0; j < 2; ++j) {
                acc[i][j] = __builtin_amdgcn_mfma_f32_16x16x32_bf16(bh[j], ah[i], acc[i][j], 0, 0, 0);
                acc[i][j] = __builtin_amdgcn_mfma_f32_16x16x32_bf16(bh[j], al[i], acc[i][j], 0, 0, 0);
                acc[i][j] = __builtin_amdgcn_mfma_f32_16x16x32_bf16(bl[j], ah[i], acc[i][j], 0, 0, 0);
            }
    }

    // ---- mask + scale ----
    bool rok[4];
    #pragma unroll
    for (int i = 0; i < 4; ++i)
        rok[i] = sav[lb + lhalf * 64 + i * 16 + l15] > 0.0f;
    bool cok[2][4];
    #pragma unroll
    for (int j = 0; j < 2; ++j)
        #pragma unroll
        for (int r = 0; r < 4; ++r)
            cok[j][r] = sai[sb + sq * 32 + j * 16 + g * 4 + r] > 0.0f;
    #pragma unroll
    for (int i = 0; i < 4; ++i)
        #pragma unroll
        for (int j = 0; j < 2; ++j)
            #pragma unroll
            for (int r = 0; r < 4; ++r)
                acc[i][j][r] = (rok[i] && cok[j][r]) ? acc[i][j][r] * SCALE : NEGV;

    // ---- per-lane row argmax over (j,r): s ascending, strict > = first-max ----
    #pragma unroll
    for (int i = 0; i < 4; ++i) {
        float v = acc[i][0][0];
        int ci = sb + sq * 32 + g * 4;          // j=0, r=0
        #pragma unroll
        for (int j = 0; j < 2; ++j)
            #pragma unroll
            for (int r = 0; r < 4; ++r) {
                if (j == 0 && r == 0) continue;
                float x = acc[i][j][r];
                int cx = sb + sq * 32 + j * 16 + g * 4 + r;
                bool up = x > v;
                v = up ? x : v;
                ci = up ? cx : ci;
            }
        rowbuf[lhalf * 64 + i * 16 + l15][sq * 4 + g] =
            ((u64)encf(v) << 32) | (unsigned)(~(unsigned)ci);
    }

    // ---- per-lane col max over i (value only) ----
    #pragma unroll
    for (int j = 0; j < 2; ++j)
        #pragma unroll
        for (int r = 0; r < 4; ++r) {
            float m = acc[0][j][r];
            #pragma unroll
            for (int i = 1; i < 4; ++i) m = fmaxf(m, acc[i][j][r]);
            colbuf[sq * 32 + j * 16 + g * 4 + r][lhalf * 16 + l15] = m;
        }

    __syncthreads();

    if (tid < 128) {
        // row scan: 16 u64 entries, packed max preserves first-index ties
        u64 m = rowbuf[tid][0];
        #pragma unroll
        for (int e = 1; e < 16; ++e) {
            u64 x = rowbuf[tid][e];
            m = (x > m) ? x : m;
        }
        rowpart[(size_t)sbi * LDIM + lb + tid] = m;     // plain store, no atomic
    } else if (tid < 256) {
        int c = tid - 128;
        float m = colbuf[c][0];
        #pragma unroll
        for (int e = 1; e < 32; ++e) m = fmaxf(m, colbuf[c][e]);
        colpart[(size_t)lbi * LDIM + sb + c] = m;       // plain store, no atomic
    }
}

// fcol: reduce 50 col partials per column -> encoded colmax
__global__ __launch_bounds__(256) void fcol_kernel(
        const float* __restrict__ colpart, unsigned* __restrict__ colenc) {
    int s = blockIdx.x * 256 + threadIdx.x;
    if (s >= LDIM) return;
    float m = colpart[s];
    #pragma unroll 7
    for (int p = 1; p < 50; ++p) m = fmaxf(m, colpart[(size_t)p * LDIM + s]);
    colenc[s] = encf(m);
}

// frow: reduce 50 row partials, mutual-NN check, write mkpts1/mask_v/score
__global__ __launch_bounds__(256) void frow_kernel(
        const u64* __restrict__ rowpart, const unsigned* __restrict__ colenc,
        float* __restrict__ out) {
    int l = blockIdx.x * 256 + threadIdx.x;
    if (l >= LDIM) return;
    u64 m = rowpart[l];
    #pragma unroll 7
    for (int p = 1; p < 50; ++p) {
        u64 x = rowpart[(size_t)p * LDIM + l];
        m = (x > m) ? x : m;
    }
    unsigned enc = (unsigned)(m >> 32);
    unsigned s = ~((unsigned)m);          // row argmax column (first on ties)
    float val = decf(enc);
    bool mk = (enc == colenc[s]) && (val > 0.0f);
    int aj = mk ? (int)s : 0;             // argmax(mask) == 0 when mask row empty
    out[12800 + 2 * l]     = (float)((aj % WDIM) * 8);
    out[12800 + 2 * l + 1] = (float)((aj / WDIM) * 8);
    out[25600 + l] = mk ? 1.0f : 0.0f;
    out[32000 + l] = mk ? val : 0.0f;
}

// ---------------- fallback fp32 path (used only if workspace too small) ------

__global__ void init_kernel(u64* __restrict__ rowp,
                            unsigned* __restrict__ colenc,
                            float* __restrict__ out) {
    int i = blockIdx.x * 256 + threadIdx.x;
    if (i < LDIM) {
        rowp[i] = 0ull;
        colenc[i] = 0u;
        out[2 * i]     = (float)((i % WDIM) * 8);
        out[2 * i + 1] = (float)((i / WDIM) * 8);
    }
}

__global__ __launch_bounds__(256, 4) void main_kernel(
        const float* __restrict__ A, const float* __restrict__ B,
        const float* __restrict__ sav, const float* __restrict__ sai,
        u64* __restrict__ rowp, unsigned* __restrict__ colenc,
        float* __restrict__ out) {
    __shared__ float As[32][128];
    __shared__ float Bs[32][128];
    const int tid = threadIdx.x;
    const int b = blockIdx.x;

    if (b >= 2500) {
        int i = (b - 2500) * 256 + tid;
        int oy = i / 640, ox = i % 640;
        const float step = 79.0f / 639.0f;
        float fy = (float)oy * step;
        float fx = (float)ox * step;
        int y0 = (int)floorf(fy); if (y0 > 79) y0 = 79; if (y0 < 0) y0 = 0;
        int x0 = (int)floorf(fx); if (x0 > 79) x0 = 79; if (x0 < 0) x0 = 0;
        int y1 = (y0 + 1 < 80) ? y0 + 1 : 79;
        int x1 = (x0 + 1 < 80) ? x0 + 1 : 79;
        float wy = fy - (float)y0;
        float wx = fx - (float)x0;
        float v00 = sai[y0 * 80 + x0], v01 = sai[y0 * 80 + x1];
        float v10 = sai[y1 * 80 + x0], v11 = sai[y1 * 80 + x1];
        float r0 = v00 * (1.0f - wy) + v10 * wy;
        float r1 = v01 * (1.0f - wy) + v11 * wy;
        out[38400 + i] = r0 * (1.0f - wx) + r1 * wx;
        return;
    }

    const int lb = (b / 50) * 128;
    const int sb = (b % 50) * 128;
    const int tx = tid & 15, ty = tid >> 4;

    float acc[8][8];
    #pragma unroll
    for (int i = 0; i < 8; ++i)
        #pragma unroll
        for (int j = 0; j < 8; ++j) acc[i][j] = 0.0f;

    float4* As4 = (float4*)As;
    float4* Bs4 = (float4*)Bs;
    const float4* pA = (const float4*)As;
    const float4* pB = (const float4*)Bs;

    for (int kb = 0; kb < 2; ++kb) {
        #pragma unroll
        for (int i = tid, it = 0; it < 4; i += 256, ++it) {
            int c = i >> 5, q = i & 31;
            As4[i] = ((const float4*)(A + (kb * 32 + c) * LDIM + lb))[q];
            Bs4[i] = ((const float4*)(B + (kb * 32 + c) * LDIM + sb))[q];
        }
        __syncthreads();

        #pragma unroll 4
        for (int c = 0; c < 32; ++c) {
            float4 a0 = pA[(c << 5) + ty];
            float4 a1 = pA[(c << 5) + ty + 16];
            float4 b0 = pB[(c << 5) + tx];
            float4 b1 = pB[(c << 5) + tx + 16];
            float av[8] = {a0.x, a0.y, a0.z, a0.w, a1.x, a1.y, a1.z, a1.w};
            float bv[8] = {b0.x, b0.y, b0.z, b0.w, b1.x, b1.y, b1.z, b1.w};
            #pragma unroll
            for (int i = 0; i < 8; ++i)
                #pragma unroll
                for (int j = 0; j < 8; ++j)
                    acc[i][j] = fmaf(av[i], bv[j], acc[i][j]);
        }
        __syncthreads();
    }

    int rg[8], cg[8];
    #pragma unroll
    for (int i = 0; i < 8; ++i) {
        rg[i] = lb + ty * 4 + ((i < 4) ? i : (64 + i - 4));
        cg[i] = sb + tx * 4 + ((i < 4) ? i : (64 + i - 4));
    }
    bool rok[8], cok[8];
    #pragma unroll
    for (int i = 0; i < 8; ++i) rok[i] = sav[rg[i]] > 0.0f;
    #pragma unroll
    for (int j = 0; j < 8; ++j) cok[j] = sai[cg[j]] > 0.0f;

    float conf[8][8];
    #pragma unroll
    for (int i = 0; i < 8; ++i)
        #pragma unroll
        for (int j = 0; j < 8; ++j)
            conf[i][j] = (rok[i] && cok[j]) ? acc[i][j] * 0.15625f : NEGV;

    #pragma unroll
    for (int i = 0; i < 8; ++i) {
        float v = conf[i][0];
        int ci = cg[0];
        #pragma unroll
        for (int j = 1; j < 8; ++j) {
            bool up = conf[i][j] > v;
            v = up ? conf[i][j] : v;
            ci = up ? cg[j] : ci;
        }
        #pragma unroll
        for (int d = 1; d < 16; d <<= 1) {
            float ov = __shfl_xor(v, d, 64);
            int oi = __shfl_xor(ci, d, 64);
            bool take = (ov > v) || ((ov == v) && (oi < ci));
            v = take ? ov : v;
            ci = take ? oi : ci;
        }
        if (tx == 0)
            atomicMax(&rowp[rg[i]],
                      ((u64)encf(v) << 32) | (unsigned)(~(unsigned)ci));
    }

    __syncthreads();
    float* cred = &As[0][0];
    #pragma unroll
    for (int j = 0; j < 8; ++j) {
        float m = conf[0][j];
        #pragma unroll
        for (int i = 1; i < 8; ++i) m = fmaxf(m, conf[i][j]);
        int cl = tx * 4 + ((j < 4) ? j : (64 + j - 4));
        cred[cl * 17 + ty] = m;
    }
    __syncthreads();
    if (tid < 128) {
        float m = cred[tid * 17];
        #pragma unroll
        for (int t = 1; t < 16; ++t) m = fmaxf(m, cred[tid * 17 + t]);
        atomicMax(&colenc[sb + tid], encf(m));
    }
}

__global__ void finalize_kernel(const u64* __restrict__ rowp,
                                const unsigned* __restrict__ colenc,
                                float* __restrict__ out) {
    int l = blockIdx.x * 256 + threadIdx.x;
    if (l >= LDIM) return;
    u64 p = rowp[l];
    unsigned enc = (unsigned)(p >> 32);
    unsigned s = ~((unsigned)p);
    float val = decf(enc);
    bool mk = (enc == colenc[s]) && (val > 0.0f);
    int aj = mk ? (int)s : 0;
    out[12800 + 2 * l]     = (float)((aj % WDIM) * 8);
    out[12800 + 2 * l + 1] = (float)((aj / WDIM) * 8);
    out[25600 + l] = mk ? 1.0f : 0.0f;
    out[32000 + l] = mk ? val : 0.0f;
}

extern "C" void kernel_launch(void* const* d_in, const int* in_sizes, int n_in,
                              void* d_out, int out_size, void* d_ws, size_t ws_size,
                              hipStream_t stream) {
    const float* frv = (const float*)d_in[0];  // feat_reg_vi [64,6400]
    const float* fri = (const float*)d_in[1];  // feat_reg_ir [64,6400]
    const float* sav = (const float*)d_in[2];  // feat_sa_vi  [6400]
    const float* sai = (const float*)d_in[3];  // feat_sa_ir  [6400]
    float* out = (float*)d_out;
    char* ws = (char*)d_ws;

    if (ws_size >= (size_t)WS_NEEDED) {
        unsigned* colenc = (unsigned*)(ws + COLE_OFF);
        u16* Ahi = (u16*)(ws + AHI_OFF);
        u16* Alo = (u16*)(ws + ALO_OFF);
        u16* Bhi = (u16*)(ws + BHI_OFF);
        u16* Blo = (u16*)(ws + BLO_OFF);
        u64* rowpart = (u64*)(ws + ROWPART_OFF);
        float* colpart = (float*)(ws + COLPART_OFF);
        prep_kernel<<<200, 256, 0, stream>>>(frv, fri, Ahi, Alo, Bhi, Blo, out);
        main_mfma<<<3300, 512, 0, stream>>>(Ahi, Alo, Bhi, Blo, sav, sai,
                                            rowpart, colpart, out);
        fcol_kernel<<<25, 256, 0, stream>>>(colpart, colenc);
        frow_kernel<<<25, 256, 0, stream>>>(rowpart, colenc, out);
    } else {
        u64* rowp = (u64*)(ws + ROWPART_OFF % 8 == 0 ? ws + ROWPART_OFF : ws);
        unsigned* colenc = (unsigned*)(ws + COLE_OFF);
        rowp = (u64*)(ws + 25600);   // fallback scratch (rowp after colenc)
        init_kernel<<<25, 256, 0, stream>>>(rowp, colenc, out);
        main_kernel<<<4100, 256, 0, stream>>>(frv, fri, sav, sai,
                                              rowp, colenc, out);
        finalize_kernel<<<25, 256, 0, stream>>>(rowp, colenc, out);
    }
}

// Round 4
// 88.660 us; speedup vs baseline: 1.2095x; 1.2095x over previous
//
#include <hip/hip_runtime.h>

// Problem constants (N=1, C=64, H=W=80)
#define LDIM 6400
#define CDIM 64
#define WDIM 80
#define NEGV -1e9f
#define SCALE 0.15625f   // 1/(sqrt(64)*sqrt(64)*0.1) = 1/6.4

typedef unsigned short u16;
typedef unsigned long long u64;
typedef __attribute__((ext_vector_type(8))) short bf16x8;   // 8 bf16 = 4 VGPRs
typedef __attribute__((ext_vector_type(4))) float f32x4;
typedef __attribute__((ext_vector_type(4))) unsigned uint4e;

// Workspace layout (bytes) -- R2 layout (atomics need zero-init in prep)
#define ROWP_OFF 0                             // 6400 u64
#define COLE_OFF (LDIM * 8)                    // 51200: 6400 u32
#define AHI_OFF  (COLE_OFF + LDIM * 4)         // 76800 (16B aligned)
#define ARR_BYTES (LDIM * CDIM * 2)            // 819200 per bf16 array
#define ALO_OFF  (AHI_OFF + ARR_BYTES)
#define BHI_OFF  (ALO_OFF + ARR_BYTES)
#define BLO_OFF  (BHI_OFF + ARR_BYTES)
#define WS_NEEDED (BLO_OFF + ARR_BYTES)        // ~3.35 MB

// Orderable (ascending) encoding of fp32.
__device__ __forceinline__ unsigned encf(float f) {
    unsigned b = __float_as_uint(f);
    return (b & 0x80000000u) ? ~b : (b | 0x80000000u);
}
__device__ __forceinline__ float decf(unsigned e) {
    unsigned b = (e & 0x80000000u) ? (e ^ 0x80000000u) : ~e;
    return __uint_as_float(b);
}

// Split fp32 into bf16 hi (truncated, exact in f32) + bf16 lo (RNE of residual).
__device__ __forceinline__ void splitbf(float a, u16& h, u16& l) {
    unsigned ub = __float_as_uint(a);
    unsigned hb = ub & 0xFFFF0000u;
    float lof = a - __uint_as_float(hb);      // exact
    unsigned lb_ = __float_as_uint(lof);
    h = (u16)(hb >> 16);
    l = (u16)((lb_ + 0x7FFFu + ((lb_ >> 16) & 1u)) >> 16);
}

// global -> LDS direct copy, 16B per lane. LDS dest is wave-uniform base;
// HW adds lane*16. Global src is per-lane.
typedef __attribute__((address_space(1))) const unsigned as1_u32;
typedef __attribute__((address_space(3))) unsigned as3_u32;
__device__ __forceinline__ void gl_lds16(const u16* g, u16* l) {
    __builtin_amdgcn_global_load_lds((as1_u32*)g, (as3_u32*)l, 16, 0, 0);
}

// prep: zero rowp/colenc + mkpts0 + convert A,B -> FRAG-MAJOR bf16 hi/lo.
// Frag-major layout (u16 units): elem(row l, k) at
//   (l>>4)*1024 + ks*512 + g*128 + (l&15)*8 + e   where k = ks*32 + g*8 + e.
// => a wave's 16x32 MFMA fragment is ONE contiguous 1KB load at base+lane*16,
// and a 128-row panel is 16KB CONTIGUOUS (=> global_load_lds staging).
__global__ __launch_bounds__(256) void prep_kernel(
        const float* __restrict__ A, const float* __restrict__ B,
        u16* __restrict__ Ahi, u16* __restrict__ Alo,
        u16* __restrict__ Bhi, u16* __restrict__ Blo,
        u64* __restrict__ rowp, unsigned* __restrict__ colenc,
        float* __restrict__ out) {
    int bi = blockIdx.x;
    const float* src;
    u16 *dhi, *dlo;
    bool isA = bi < 100;
    if (isA) { src = A; dhi = Ahi; dlo = Alo; }
    else     { src = B; dhi = Bhi; dlo = Blo; bi -= 100; }
    const int t = threadIdx.x;
    const int l = bi * 64 + (t & 63);
    const int kq = t >> 6;                      // 0..3: k in [kq*16, kq*16+16)
    const int ks = kq >> 1;                     // k-step (32-wide)
    const int g0 = (kq & 1) * 2;                // first of two 8-wide chunks

    unsigned hp[8], lp[8];
    #pragma unroll
    for (int m = 0; m < 8; ++m) {
        int k = kq * 16 + 2 * m;
        u16 h0, l0, h1, l1;
        splitbf(src[k * LDIM + l], h0, l0);
        splitbf(src[(k + 1) * LDIM + l], h1, l1);
        hp[m] = (unsigned)h0 | ((unsigned)h1 << 16);
        lp[m] = (unsigned)l0 | ((unsigned)l1 << 16);
    }
    size_t base = (size_t)(l >> 4) * 1024 + (size_t)ks * 512 + (size_t)(l & 15) * 8;
    *(uint4e*)(dhi + base + g0 * 128)       = (uint4e){hp[0], hp[1], hp[2], hp[3]};
    *(uint4e*)(dhi + base + (g0 + 1) * 128) = (uint4e){hp[4], hp[5], hp[6], hp[7]};
    *(uint4e*)(dlo + base + g0 * 128)       = (uint4e){lp[0], lp[1], lp[2], lp[3]};
    *(uint4e*)(dlo + base + (g0 + 1) * 128) = (uint4e){lp[4], lp[5], lp[6], lp[7]};

    if (isA && kq == 0) {
        rowp[l] = 0ull;
        colenc[l] = 0u;
        out[2 * l]     = (float)((l % WDIM) * 8);
        out[2 * l + 1] = (float)((l / WDIM) * 8);
    }
}

// main (MFMA v4): blocks [0,2500) = 128x128 conf tiles, 512 threads = 8 waves
// in 2(lhalf) x 4(sq); wave tile 64(l) x 32(s). Operand-swapped MFMA:
// D = mfma(Bfrag, Afrag) -> D[row=s][col=l], per lane (g=lane>>4, l15=lane&15):
//   s = sb + sq*32 + j*16 + g*4 + r   (in-lane row-argmax)
//   l = lb + lhalf*64 + i*16 + l15    (cross-lane col-max via LDS)
// A panel (Ahi+Alo, 32KB) staged ONCE into LDS via global_load_lds (kills the
// 4x redundant per-wave A fetches: 192 -> 96 KB L2 traffic per block); B loaded
// direct (only 2x redundant). LDS region reused by epilogue buffers after a
// barrier -> ~34.8 KB total, keeps 4 blocks/CU. Epilogue = R2's proven
// atomicMax (fire-and-forget; R3 showed split-reduce kernels cost MORE).
// Blocks [2500,3300) = bilinear x8 upsample (backfills the tail).
__global__ __launch_bounds__(512, 4) void main_mfma(
        const u16* __restrict__ Ahi, const u16* __restrict__ Alo,
        const u16* __restrict__ Bhi, const u16* __restrict__ Blo,
        const float* __restrict__ sav, const float* __restrict__ sai,
        u64* __restrict__ rowp, unsigned* __restrict__ colenc,
        float* __restrict__ out) {
    const int tid = threadIdx.x;
    const int b = blockIdx.x;

    if (b >= 2500) {
        // ---- upsample path ----
        int i = (b - 2500) * 512 + tid;   // < 640*640 = 409600, exact
        int oy = i / 640, ox = i % 640;
        const float step = 79.0f / 639.0f;
        float fy = (float)oy * step;
        float fx = (float)ox * step;
        int y0 = (int)floorf(fy); if (y0 > 79) y0 = 79; if (y0 < 0) y0 = 0;
        int x0 = (int)floorf(fx); if (x0 > 79) x0 = 79; if (x0 < 0) x0 = 0;
        int y1 = (y0 + 1 < 80) ? y0 + 1 : 79;
        int x1 = (x0 + 1 < 80) ? x0 + 1 : 79;
        float wy = fy - (float)y0;
        float wx = fx - (float)x0;
        float v00 = sai[y0 * 80 + x0], v01 = sai[y0 * 80 + x1];
        float v10 = sai[y1 * 80 + x0], v11 = sai[y1 * 80 + x1];
        float r0 = v00 * (1.0f - wy) + v10 * wy;
        float r1 = v01 * (1.0f - wy) + v11 * wy;
        out[38400 + i] = r0 * (1.0f - wx) + r1 * wx;
        return;
    }

    // 34816 B shared: phase 1 = staged A panel (Ahi 16K @0, Alo 16K @16K);
    // phase 2 (after barrier) = rowbuf u64[128][17] (17408) + colbuf f32[128][33]
    __attribute__((aligned(16))) __shared__ char smem[34816];
    u16* sAh = (u16*)smem;              // 8192 u16
    u16* sAl = (u16*)(smem + 16384);    // 8192 u16
    u64  (*rowbuf)[17] = (u64 (*)[17])smem;
    float (*colbuf)[33] = (float (*)[33])(smem + 17408);

    // ---- conf tile path ----
    const int lb = (b / 50) * 128;
    const int sb = (b % 50) * 128;
    const int lane = tid & 63, wid = tid >> 6;
    const int l15 = lane & 15, g = lane >> 4;
    const int lhalf = wid >> 2, sq = wid & 3;

    // ---- stage A panel: 2x16KB contiguous, 16 wave-chunks of 1KB per array ----
    {
        const u16* Ah_pan = Ahi + (size_t)(lb >> 4) * 1024;
        const u16* Al_pan = Alo + (size_t)(lb >> 4) * 1024;
        #pragma unroll
        for (int c = 0; c < 2; ++c) {
            int chunk = wid * 2 + c;              // 0..15, wave-uniform
            gl_lds16(Ah_pan + chunk * 512 + lane * 8, sAh + chunk * 512);
            gl_lds16(Al_pan + chunk * 512 + lane * 8, sAl + chunk * 512);
        }
    }

    f32x4 acc[4][2];
    #pragma unroll
    for (int i = 0; i < 4; ++i)
        #pragma unroll
        for (int j = 0; j < 2; ++j)
            #pragma unroll
            for (int e = 0; e < 4; ++e) acc[i][j][e] = 0.0f;

    // B frag bases (u16 units); one coalesced 1KB load per fragment
    const u16* pBh = Bhi + (size_t)(sb / 16 + sq * 2) * 1024 + lane * 8;
    const u16* pBl = Blo + (size_t)(sb / 16 + sq * 2) * 1024 + lane * 8;
    // A frag LDS offsets (u16 units): frag-group f = lhalf*4 + i
    const int aoff = (lhalf * 4) * 1024 + lane * 8;

    __syncthreads();   // staged A visible (vmcnt drained by barrier)

    #pragma unroll
    for (int ks = 0; ks < 2; ++ks) {
        bf16x8 ah[4], al[4], bh[2], bl[2];
        #pragma unroll
        for (int j = 0; j < 2; ++j) {
            bh[j] = *(const bf16x8*)(pBh + (size_t)j * 1024 + ks * 512);
            bl[j] = *(const bf16x8*)(pBl + (size_t)j * 1024 + ks * 512);
        }
        #pragma unroll
        for (int i = 0; i < 4; ++i) {
            ah[i] = *(const bf16x8*)(sAh + aoff + i * 1024 + ks * 512);
            al[i] = *(const bf16x8*)(sAl + aoff + i * 1024 + ks * 512);
        }
        #pragma unroll
        for (int i = 0; i < 4; ++i)
            #pragma unroll
            for (int j = 0; j < 2; ++j) {
                acc[i][j] = __builtin_amdgcn_mfma_f32_16x16x32_bf16(bh[j], ah[i], acc[i][j], 0, 0, 0);
                acc[i][j] = __builtin_amdgcn_mfma_f32_16x16x32_bf16(bh[j], al[i], acc[i][j], 0, 0, 0);
                acc[i][j] = __builtin_amdgcn_mfma_f32_16x16x32_bf16(bl[j], ah[i], acc[i][j], 0, 0, 0);
            }
    }

    // ---- mask + scale ----
    bool rok[4];
    #pragma unroll
    for (int i = 0; i < 4; ++i)
        rok[i] = sav[lb + lhalf * 64 + i * 16 + l15] > 0.0f;
    bool cok[2][4];
    #pragma unroll
    for (int j = 0; j < 2; ++j)
        #pragma unroll
        for (int r = 0; r < 4; ++r)
            cok[j][r] = sai[sb + sq * 32 + j * 16 + g * 4 + r] > 0.0f;
    #pragma unroll
    for (int i = 0; i < 4; ++i)
        #pragma unroll
        for (int j = 0; j < 2; ++j)
            #pragma unroll
            for (int r = 0; r < 4; ++r)
                acc[i][j][r] = (rok[i] && cok[j][r]) ? acc[i][j][r] * SCALE : NEGV;

    __syncthreads();   // all A-frag ds_reads done: safe to overwrite smem

    // ---- per-lane row argmax over (j,r): s ascending, strict > = first-max ----
    #pragma unroll
    for (int i = 0; i < 4; ++i) {
        float v = acc[i][0][0];
        int ci = sb + sq * 32 + g * 4;          // j=0, r=0
        #pragma unroll
        for (int j = 0; j < 2; ++j)
            #pragma unroll
            for (int r = 0; r < 4; ++r) {
                if (j == 0 && r == 0) continue;
                float x = acc[i][j][r];
                int cx = sb + sq * 32 + j * 16 + g * 4 + r;
                bool up = x > v;
                v = up ? x : v;
                ci = up ? cx : ci;
            }
        rowbuf[lhalf * 64 + i * 16 + l15][sq * 4 + g] =
            ((u64)encf(v) << 32) | (unsigned)(~(unsigned)ci);
    }

    // ---- per-lane col max over i (value only) ----
    #pragma unroll
    for (int j = 0; j < 2; ++j)
        #pragma unroll
        for (int r = 0; r < 4; ++r) {
            float m = acc[0][j][r];
            #pragma unroll
            for (int i = 1; i < 4; ++i) m = fmaxf(m, acc[i][j][r]);
            colbuf[sq * 32 + j * 16 + g * 4 + r][lhalf * 16 + l15] = m;
        }

    __syncthreads();

    if (tid < 128) {
        // row scan: 16 u64 entries, packed max preserves first-index ties
        u64 m = rowbuf[tid][0];
        #pragma unroll
        for (int e = 1; e < 16; ++e) {
            u64 x = rowbuf[tid][e];
            m = (x > m) ? x : m;
        }
        atomicMax(&rowp[lb + tid], m);          // no-return atomic: fire & forget
    } else if (tid < 256) {
        int c = tid - 128;
        float m = colbuf[c][0];
        #pragma unroll
        for (int e = 1; e < 32; ++e) m = fmaxf(m, colbuf[c][e]);
        atomicMax(&colenc[sb + c], encf(m));
    }
}

// finalize: mutual-NN check + write mkpts1/mask_v/score
__global__ void finalize_kernel(const u64* __restrict__ rowp,
                                const unsigned* __restrict__ colenc,
                                float* __restrict__ out) {
    int l = blockIdx.x * 256 + threadIdx.x;
    if (l >= LDIM) return;
    u64 p = rowp[l];
    unsigned enc = (unsigned)(p >> 32);
    unsigned s = ~((unsigned)p);          // row argmax column (first on ties)
    float val = decf(enc);
    bool mk = (enc == colenc[s]) && (val > 0.0f);
    int aj = mk ? (int)s : 0;             // argmax(mask) == 0 when mask row empty
    out[12800 + 2 * l]     = (float)((aj % WDIM) * 8);
    out[12800 + 2 * l + 1] = (float)((aj / WDIM) * 8);
    out[25600 + l] = mk ? 1.0f : 0.0f;
    out[32000 + l] = mk ? val : 0.0f;
}

// ---------------- fallback fp32 path (used only if workspace too small) ------

__global__ void init_kernel(u64* __restrict__ rowp,
                            unsigned* __restrict__ colenc,
                            float* __restrict__ out) {
    int i = blockIdx.x * 256 + threadIdx.x;
    if (i < LDIM) {
        rowp[i] = 0ull;
        colenc[i] = 0u;
        out[2 * i]     = (float)((i % WDIM) * 8);
        out[2 * i + 1] = (float)((i / WDIM) * 8);
    }
}

__global__ __launch_bounds__(256, 4) void main_kernel(
        const float* __restrict__ A, const float* __restrict__ B,
        const float* __restrict__ sav, const float* __restrict__ sai,
        u64* __restrict__ rowp, unsigned* __restrict__ colenc,
        float* __restrict__ out) {
    __shared__ float As[32][128];
    __shared__ float Bs[32][128];
    const int tid = threadIdx.x;
    const int b = blockIdx.x;

    if (b >= 2500) {
        int i = (b - 2500) * 256 + tid;
        int oy = i / 640, ox = i % 640;
        const float step = 79.0f / 639.0f;
        float fy = (float)oy * step;
        float fx = (float)ox * step;
        int y0 = (int)floorf(fy); if (y0 > 79) y0 = 79; if (y0 < 0) y0 = 0;
        int x0 = (int)floorf(fx); if (x0 > 79) x0 = 79; if (x0 < 0) x0 = 0;
        int y1 = (y0 + 1 < 80) ? y0 + 1 : 79;
        int x1 = (x0 + 1 < 80) ? x0 + 1 : 79;
        float wy = fy - (float)y0;
        float wx = fx - (float)x0;
        float v00 = sai[y0 * 80 + x0], v01 = sai[y0 * 80 + x1];
        float v10 = sai[y1 * 80 + x0], v11 = sai[y1 * 80 + x1];
        float r0 = v00 * (1.0f - wy) + v10 * wy;
        float r1 = v01 * (1.0f - wy) + v11 * wy;
        out[38400 + i] = r0 * (1.0f - wx) + r1 * wx;
        return;
    }

    const int lb = (b / 50) * 128;
    const int sb = (b % 50) * 128;
    const int tx = tid & 15, ty = tid >> 4;

    float acc[8][8];
    #pragma unroll
    for (int i = 0; i < 8; ++i)
        #pragma unroll
        for (int j = 0; j < 8; ++j) acc[i][j] = 0.0f;

    float4* As4 = (float4*)As;
    float4* Bs4 = (float4*)Bs;
    const float4* pA = (const float4*)As;
    const float4* pB = (const float4*)Bs;

    for (int kb = 0; kb < 2; ++kb) {
        #pragma unroll
        for (int i = tid, it = 0; it < 4; i += 256, ++it) {
            int c = i >> 5, q = i & 31;
            As4[i] = ((const float4*)(A + (kb * 32 + c) * LDIM + lb))[q];
            Bs4[i] = ((const float4*)(B + (kb * 32 + c) * LDIM + sb))[q];
        }
        __syncthreads();

        #pragma unroll 4
        for (int c = 0; c < 32; ++c) {
            float4 a0 = pA[(c << 5) + ty];
            float4 a1 = pA[(c << 5) + ty + 16];
            float4 b0 = pB[(c << 5) + tx];
            float4 b1 = pB[(c << 5) + tx + 16];
            float av[8] = {a0.x, a0.y, a0.z, a0.w, a1.x, a1.y, a1.z, a1.w};
            float bv[8] = {b0.x, b0.y, b0.z, b0.w, b1.x, b1.y, b1.z, b1.w};
            #pragma unroll
            for (int i = 0; i < 8; ++i)
                #pragma unroll
                for (int j = 0; j < 8; ++j)
                    acc[i][j] = fmaf(av[i], bv[j], acc[i][j]);
        }
        __syncthreads();
    }

    int rg[8], cg[8];
    #pragma unroll
    for (int i = 0; i < 8; ++i) {
        rg[i] = lb + ty * 4 + ((i < 4) ? i : (64 + i - 4));
        cg[i] = sb + tx * 4 + ((i < 4) ? i : (64 + i - 4));
    }
    bool rok[8], cok[8];
    #pragma unroll
    for (int i = 0; i < 8; ++i) rok[i] = sav[rg[i]] > 0.0f;
    #pragma unroll
    for (int j = 0; j < 8; ++j) cok[j] = sai[cg[j]] > 0.0f;

    float conf[8][8];
    #pragma unroll
    for (int i = 0; i < 8; ++i)
        #pragma unroll
        for (int j = 0; j < 8; ++j)
            conf[i][j] = (rok[i] && cok[j]) ? acc[i][j] * 0.15625f : NEGV;

    #pragma unroll
    for (int i = 0; i < 8; ++i) {
        float v = conf[i][0];
        int ci = cg[0];
        #pragma unroll
        for (int j = 1; j < 8; ++j) {
            bool up = conf[i][j] > v;
            v = up ? conf[i][j] : v;
            ci = up ? cg[j] : ci;
        }
        #pragma unroll
        for (int d = 1; d < 16; d <<= 1) {
            float ov = __shfl_xor(v, d, 64);
            int oi = __shfl_xor(ci, d, 64);
            bool take = (ov > v) || ((ov == v) && (oi < ci));
            v = take ? ov : v;
            ci = take ? oi : ci;
        }
        if (tx == 0)
            atomicMax(&rowp[rg[i]],
                      ((u64)encf(v) << 32) | (unsigned)(~(unsigned)ci));
    }

    __syncthreads();
    float* cred = &As[0][0];
    #pragma unroll
    for (int j = 0; j < 8; ++j) {
        float m = conf[0][j];
        #pragma unroll
        for (int i = 1; i < 8; ++i) m = fmaxf(m, conf[i][j]);
        int cl = tx * 4 + ((j < 4) ? j : (64 + j - 4));
        cred[cl * 17 + ty] = m;
    }
    __syncthreads();
    if (tid < 128) {
        float m = cred[tid * 17];
        #pragma unroll
        for (int t = 1; t < 16; ++t) m = fmaxf(m, cred[tid * 17 + t]);
        atomicMax(&colenc[sb + tid], encf(m));
    }
}

extern "C" void kernel_launch(void* const* d_in, const int* in_sizes, int n_in,
                              void* d_out, int out_size, void* d_ws, size_t ws_size,
                              hipStream_t stream) {
    const float* frv = (const float*)d_in[0];  // feat_reg_vi [64,6400]
    const float* fri = (const float*)d_in[1];  // feat_reg_ir [64,6400]
    const float* sav = (const float*)d_in[2];  // feat_sa_vi  [6400]
    const float* sai = (const float*)d_in[3];  // feat_sa_ir  [6400]
    float* out = (float*)d_out;
    char* ws = (char*)d_ws;

    u64* rowp = (u64*)(ws + ROWP_OFF);
    unsigned* colenc = (unsigned*)(ws + COLE_OFF);

    if (ws_size >= (size_t)WS_NEEDED) {
        u16* Ahi = (u16*)(ws + AHI_OFF);
        u16* Alo = (u16*)(ws + ALO_OFF);
        u16* Bhi = (u16*)(ws + BHI_OFF);
        u16* Blo = (u16*)(ws + BLO_OFF);
        prep_kernel<<<200, 256, 0, stream>>>(frv, fri, Ahi, Alo, Bhi, Blo,
                                             rowp, colenc, out);
        main_mfma<<<3300, 512, 0, stream>>>(Ahi, Alo, Bhi, Blo, sav, sai,
                                            rowp, colenc, out);
        finalize_kernel<<<25, 256, 0, stream>>>(rowp, colenc, out);
    } else {
        init_kernel<<<25, 256, 0, stream>>>(rowp, colenc, out);
        main_kernel<<<4100, 256, 0, stream>>>(frv, fri, sav, sai,
                                              rowp, colenc, out);
        finalize_kernel<<<25, 256, 0, stream>>>(rowp, colenc, out);
    }
}